// Round 3
// baseline (623.644 us; speedup 1.0000x reference)
//
#include <hip/hip_runtime.h>
#include <hip/hip_bf16.h>
#include <math.h>

#define HIDDEN 2048
#define NH 16
#define HD 128
#define SEQ 2048
#define BATCH 2
#define NROW (BATCH*SEQ)   // 4096

typedef unsigned short u16;
typedef unsigned int   u32;
typedef __bf16 bf16x8 __attribute__((ext_vector_type(8)));
typedef float  f32x4  __attribute__((ext_vector_type(4)));

__device__ __forceinline__ u16 f2bf(float f){
  u32 u = __float_as_uint(f);
  u32 r = (u + 0x7fffu + ((u >> 16) & 1u)) >> 16;   // RNE
  return (u16)r;
}
__device__ __forceinline__ float bf2f(u16 h){ return __uint_as_float(((u32)h) << 16); }

typedef const void __attribute__((address_space(1)))* gas1_ptr;
typedef void __attribute__((address_space(3)))*       las3_ptr;
__device__ __forceinline__ void gload16(const void* g, void* l){
  // async global->LDS, 16B/lane; LDS dest = wave-uniform base + lane*16
  __builtin_amdgcn_global_load_lds((gas1_ptr)g, (las3_ptr)l, 16, 0, 0);
}

// ---------------- cast fp32 -> bf16 ----------------
__global__ void cast_kernel(const float* __restrict__ src, u16* __restrict__ dst, int n4){
  int i = blockIdx.x * blockDim.x + threadIdx.x;
  if (i >= n4) return;
  float4 v = reinterpret_cast<const float4*>(src)[i];
  ushort4 o;
  o.x = f2bf(v.x); o.y = f2bf(v.y); o.z = f2bf(v.z); o.w = f2bf(v.w);
  reinterpret_cast<ushort4*>(dst)[i] = o;
}

// ---------------- RoPE tables: cos/sin [SEQ][64] fp32 ----------------
__global__ void rope_table_kernel(float* __restrict__ cosT, float* __restrict__ sinT){
  int i = blockIdx.x * blockDim.x + threadIdx.x;
  if (i >= SEQ * 64) return;
  int s = i >> 6, d = i & 63;
  // inv_freq = 10000^(-d/64) = exp(-d * ln(10000)/64)
  float invf = expf(-(float)d * 0.14391156830f);
  float ang = (float)s * invf;
  float sv, cv;
  sincosf(ang, &sv, &cv);   // accurate range reduction (angles up to ~2047 rad)
  cosT[i] = cv; sinT[i] = sv;
}

// ---------------- RoPE apply (in place on bf16 Q,K) ----------------
__global__ void rope_apply_kernel(u16* __restrict__ Q, u16* __restrict__ K,
                                  const float* __restrict__ cosT, const float* __restrict__ sinT){
  int i = blockIdx.x * blockDim.x + threadIdx.x;   // over NROW*NH*64
  if (i >= NROW * NH * 64) return;
  int d  = i & 63;
  int rh = i >> 6;                 // (b*SEQ+s)*NH + h
  int s  = (rh / NH) & (SEQ - 1);
  size_t base = (size_t)rh * HD;
  float c  = cosT[(s << 6) + d];
  float sn = sinT[(s << 6) + d];
  float q0 = bf2f(Q[base + d]), q1 = bf2f(Q[base + d + 64]);
  float k0 = bf2f(K[base + d]), k1 = bf2f(K[base + d + 64]);
  Q[base + d]      = f2bf(q0 * c - q1 * sn);
  Q[base + d + 64] = f2bf(q1 * c + q0 * sn);
  K[base + d]      = f2bf(k0 * c - k1 * sn);
  K[base + d + 64] = f2bf(k1 * c + k0 * sn);
}

// ---------------- GEMM C[M][N] = A[M][K] * B[N][K]^T (both bf16, K contiguous) ----------------
// m97 structure: 128x128 tile, BK=32, 4 waves (2x2), global_load_lds width 16, 2 barriers/K-step.
template<int BF16OUT>
__global__ __launch_bounds__(256) void gemm_bt_kernel(
    const u16* __restrict__ A, const u16* __restrict__ B, void* __restrict__ C,
    int M, int N, int K)
{
  __shared__ __align__(16) u16 As[128 * 32];
  __shared__ __align__(16) u16 Bs[128 * 32];
  const int tid  = threadIdx.x;
  const int wid  = tid >> 6;
  const int lane = tid & 63;
  const int lrow = lane & 15, lk = lane >> 4;
  const int wr = wid >> 1, wc = wid & 1;
  const int row0 = blockIdx.x * 128, col0 = blockIdx.y * 128;

  f32x4 acc[4][4];
  #pragma unroll
  for (int m = 0; m < 4; m++)
    #pragma unroll
    for (int n = 0; n < 4; n++) acc[m][n] = (f32x4){0.f, 0.f, 0.f, 0.f};

  const int arow = tid >> 2;            // 0..63 per staging round
  const int acol = (tid & 3) * 8;
  const u16* Ag = A + (size_t)(row0 + arow) * K + acol;
  const u16* Bg = B + (size_t)(col0 + arow) * K + acol;
  u16* AsW = As + wid * 512;            // wave-uniform LDS base (bytes wid*1024)
  u16* BsW = Bs + wid * 512;

  for (int k0 = 0; k0 < K; k0 += 32){
    gload16(Ag + k0,          AsW);
    gload16(Ag + 64 * K + k0, AsW + 2048);
    gload16(Bg + k0,          BsW);
    gload16(Bg + 64 * K + k0, BsW + 2048);
    __syncthreads();
    bf16x8 af[4], bfv[4];
    #pragma unroll
    for (int m = 0; m < 4; m++) af[m]  = *(const bf16x8*)&As[(wr * 64 + m * 16 + lrow) * 32 + lk * 8];
    #pragma unroll
    for (int n = 0; n < 4; n++) bfv[n] = *(const bf16x8*)&Bs[(wc * 64 + n * 16 + lrow) * 32 + lk * 8];
    #pragma unroll
    for (int m = 0; m < 4; m++)
      #pragma unroll
      for (int n = 0; n < 4; n++)
        acc[m][n] = __builtin_amdgcn_mfma_f32_16x16x32_bf16(af[m], bfv[n], acc[m][n], 0, 0, 0);
    __syncthreads();
  }

  // epilogue: C/D layout col=lane&15, row=(lane>>4)*4+reg  [m89-verified]
  #pragma unroll
  for (int m = 0; m < 4; m++){
    const int r = row0 + wr * 64 + m * 16 + lk * 4;
    #pragma unroll
    for (int n = 0; n < 4; n++){
      const int c = col0 + wc * 64 + n * 16 + lrow;
      #pragma unroll
      for (int j = 0; j < 4; j++){
        float v = acc[m][n][j];
        if constexpr (BF16OUT) ((u16*)C)[(size_t)(r + j) * N + c] = f2bf(v);
        else                   ((float*)C)[(size_t)(r + j) * N + c] = v;
      }
    }
  }
}

// ---------------- Flash attention fwd ----------------
// grid (SEQ/64, NH, BATCH), 256 threads = 4 waves, wave = 16 Q-rows; KV tiles of 32.
__global__ __launch_bounds__(256) void attn_kernel(
    const u16* __restrict__ Q, const u16* __restrict__ K,
    const u16* __restrict__ V, u16* __restrict__ O)
{
  __shared__ __align__(16) u16 Ks[32 * 128];   // [key][d], chunk-swizzled: phys_c = c ^ (key&7)
  __shared__ __align__(16) u16 Vt[128 * 32];   // [d][key], chunk-swizzled: phys_c = c ^ ((d>>1)&3)
  __shared__ __align__(16) u16 Pl[4][16 * 32]; // per-wave P, swizzled: phys_c = c ^ ((row>>1)&3)
  const int tid = threadIdx.x, wid = tid >> 6, lane = tid & 63;
  const int lrow = lane & 15, lk = lane >> 4;
  const int b = blockIdx.z, h = blockIdx.y;
  const int q0 = blockIdx.x * 64 + wid * 16;

  // Q fragments: A[m=q][k=d], 8 contiguous bf16 per lane
  bf16x8 qf[4];
  const u16* qrow = Q + ((size_t)((b * SEQ + q0 + lrow) * NH) + h) * HD;
  #pragma unroll
  for (int kc = 0; kc < 4; kc++) qf[kc] = *(const bf16x8*)(qrow + kc * 32 + lk * 8);

  f32x4 accO[8];
  #pragma unroll
  for (int i = 0; i < 8; i++) accO[i] = (f32x4){0.f, 0.f, 0.f, 0.f};
  float mrun[4] = {-1e30f, -1e30f, -1e30f, -1e30f};
  float lrun[4] = {0.f, 0.f, 0.f, 0.f};
  const float SC = 0.08838834764831845f * 1.4426950408889634f;  // 1/sqrt(128) * log2(e)

  const int skey = tid >> 4;          // K staging: key within round
  const int spc  = tid & 15;          // phys 16B chunk
  const int vkey = tid & 31;          // V staging
  const int vdel = (tid >> 5) * 8;
  const u16* Kbase = K + ((size_t)(b * SEQ) * NH + h) * HD;
  const u16* Vbase = V + ((size_t)(b * SEQ) * NH + h) * HD;
  u16* KsW = Ks + wid * 512;          // wave-uniform base

  for (int kv = 0; kv < SEQ; kv += 32){
    __syncthreads();
    // stage K via global_load_lds, source pre-swizzled (rule #21 / m173)
    #pragma unroll
    for (int r = 0; r < 2; r++){
      int key   = r * 16 + skey;
      int cdata = spc ^ (key & 7);
      gload16(Kbase + (size_t)(kv + key) * (NH * HD) + cdata * 8, KsW + r * 2048);
    }
    // stage V transposed into Vt (reg round-trip; swizzled scatter)
    #pragma unroll
    for (int r = 0; r < 2; r++){
      int dd0 = r * 64 + vdel;
      const u16* g = Vbase + (size_t)(kv + vkey) * (NH * HD) + dd0;
      uint4 vv = *(const uint4*)g;
      #pragma unroll
      for (int j = 0; j < 8; j++){
        u32 word = (j < 2) ? vv.x : (j < 4) ? vv.y : (j < 6) ? vv.z : vv.w;
        u16 val  = (u16)((j & 1) ? (word >> 16) : (word & 0xffff));
        int dd = dd0 + j;
        int c  = (vkey >> 3) ^ ((dd >> 1) & 3);
        Vt[dd * 32 + c * 8 + (vkey & 7)] = val;
      }
    }
    __syncthreads();

    // S = Q K^T  (B-frag: n=key=lane&15, k=d contiguous)
    f32x4 accS[2];
    accS[0] = (f32x4){0.f,0.f,0.f,0.f}; accS[1] = (f32x4){0.f,0.f,0.f,0.f};
    #pragma unroll
    for (int ns = 0; ns < 2; ns++){
      int row = ns * 16 + lrow;
      #pragma unroll
      for (int kc = 0; kc < 4; kc++){
        int pc = (kc * 4 + lk) ^ (row & 7);
        bf16x8 kf = *(const bf16x8*)&Ks[row * 128 + pc * 8];
        accS[ns] = __builtin_amdgcn_mfma_f32_16x16x32_bf16(qf[kc], kf, accS[ns], 0, 0, 0);
      }
    }

    // online softmax (scaled*log2e domain); rows owned by 16-lane groups
    float su[2][4], tmax[4];
    #pragma unroll
    for (int j = 0; j < 4; j++){
      su[0][j] = accS[0][j] * SC;
      su[1][j] = accS[1][j] * SC;
      tmax[j]  = fmaxf(su[0][j], su[1][j]);
    }
    #pragma unroll
    for (int j = 0; j < 4; j++){
      #pragma unroll
      for (int m = 1; m < 16; m <<= 1) tmax[j] = fmaxf(tmax[j], __shfl_xor(tmax[j], m));
    }
    float alpha[4], p[2][4];
    #pragma unroll
    for (int j = 0; j < 4; j++){
      float mnew = fmaxf(mrun[j], tmax[j]);
      alpha[j]   = exp2f(mrun[j] - mnew);
      mrun[j]    = mnew;
      p[0][j] = exp2f(su[0][j] - mnew);
      p[1][j] = exp2f(su[1][j] - mnew);
      float rowsum = p[0][j] + p[1][j];
      #pragma unroll
      for (int m = 1; m < 16; m <<= 1) rowsum += __shfl_xor(rowsum, m);
      lrun[j] = lrun[j] * alpha[j] + rowsum;
    }
    #pragma unroll
    for (int dn = 0; dn < 8; dn++)
      #pragma unroll
      for (int j = 0; j < 4; j++) accO[dn][j] *= alpha[j];

    // P -> per-wave LDS (swizzled), then read back as A-frag
    u16* pb = &Pl[wid][0];
    #pragma unroll
    for (int ns = 0; ns < 2; ns++)
      #pragma unroll
      for (int j = 0; j < 4; j++){
        int prow = lk * 4 + j;
        int pcol = ns * 16 + lrow;
        int c = (pcol >> 3) ^ ((prow >> 1) & 3);
        pb[prow * 32 + c * 8 + (pcol & 7)] = f2bf(p[ns][j]);
      }
    int pc2 = lk ^ ((lrow >> 1) & 3);
    bf16x8 pf = *(const bf16x8*)&pb[lrow * 32 + pc2 * 8];

    // O += P V   (B-frag from Vt: n=d, k=key contiguous)
    #pragma unroll
    for (int dn = 0; dn < 8; dn++){
      int row = dn * 16 + lrow;
      int vc = lk ^ ((row >> 1) & 3);
      bf16x8 vf = *(const bf16x8*)&Vt[row * 32 + vc * 8];
      accO[dn] = __builtin_amdgcn_mfma_f32_16x16x32_bf16(pf, vf, accO[dn], 0, 0, 0);
    }
  }

  // epilogue: divide by l, store bf16 in [b][s][h*128+d] layout
  #pragma unroll
  for (int dn = 0; dn < 8; dn++){
    #pragma unroll
    for (int j = 0; j < 4; j++){
      int qq = q0 + lk * 4 + j;
      float v = accO[dn][j] / lrun[j];
      O[((size_t)(b * SEQ + qq) * NH + h) * HD + dn * 16 + lrow] = f2bf(v);
    }
  }
}

// ---------------- launch ----------------
extern "C" void kernel_launch(void* const* d_in, const int* in_sizes, int n_in,
                              void* d_out, int out_size, void* d_ws, size_t ws_size,
                              hipStream_t stream){
  const float* hs = (const float*)d_in[0];
  const float* wq = (const float*)d_in[1];
  const float* wk = (const float*)d_in[2];
  const float* wv = (const float*)d_in[3];
  const float* wo = (const float*)d_in[4];
  float* out = (float*)d_out;

  char* ws = (char*)d_ws;
  const size_t NEL_HS = (size_t)NROW * HIDDEN;    // 8,388,608
  const size_t NEL_W  = (size_t)HIDDEN * HIDDEN;  // 4,194,304
  u16* hsb = (u16*)ws; ws += NEL_HS * 2;
  u16* wqb = (u16*)ws; ws += NEL_W * 2;
  u16* wkb = (u16*)ws; ws += NEL_W * 2;
  u16* wvb = (u16*)ws; ws += NEL_W * 2;
  u16* wob = (u16*)ws; ws += NEL_W * 2;
  u16* qb  = (u16*)ws; ws += NEL_HS * 2;
  u16* kb  = (u16*)ws; ws += NEL_HS * 2;
  u16* vb  = (u16*)ws; ws += NEL_HS * 2;
  u16* ab  = (u16*)ws; ws += NEL_HS * 2;
  float* cosT = (float*)ws; ws += (size_t)SEQ * 64 * 4;
  float* sinT = (float*)ws; ws += (size_t)SEQ * 64 * 4;

  // casts
  cast_kernel<<<dim3((unsigned)(NEL_HS / 4 / 256)), dim3(256), 0, stream>>>(hs, hsb, (int)(NEL_HS / 4));
  cast_kernel<<<dim3((unsigned)(NEL_W  / 4 / 256)), dim3(256), 0, stream>>>(wq, wqb, (int)(NEL_W / 4));
  cast_kernel<<<dim3((unsigned)(NEL_W  / 4 / 256)), dim3(256), 0, stream>>>(wk, wkb, (int)(NEL_W / 4));
  cast_kernel<<<dim3((unsigned)(NEL_W  / 4 / 256)), dim3(256), 0, stream>>>(wv, wvb, (int)(NEL_W / 4));
  cast_kernel<<<dim3((unsigned)(NEL_W  / 4 / 256)), dim3(256), 0, stream>>>(wo, wob, (int)(NEL_W / 4));
  // rope tables
  rope_table_kernel<<<dim3(SEQ * 64 / 256), dim3(256), 0, stream>>>(cosT, sinT);
  // projections
  gemm_bt_kernel<1><<<dim3(NROW / 128, HIDDEN / 128), dim3(256), 0, stream>>>(hsb, wqb, qb, NROW, HIDDEN, HIDDEN);
  gemm_bt_kernel<1><<<dim3(NROW / 128, HIDDEN / 128), dim3(256), 0, stream>>>(hsb, wkb, kb, NROW, HIDDEN, HIDDEN);
  gemm_bt_kernel<1><<<dim3(NROW / 128, HIDDEN / 128), dim3(256), 0, stream>>>(hsb, wvb, vb, NROW, HIDDEN, HIDDEN);
  // rope
  rope_apply_kernel<<<dim3(NROW * NH * 64 / 256), dim3(256), 0, stream>>>(qb, kb, cosT, sinT);
  // attention
  attn_kernel<<<dim3(SEQ / 64, NH, BATCH), dim3(256), 0, stream>>>(qb, kb, vb, ab);
  // output projection (fp32 out)
  gemm_bt_kernel<0><<<dim3(NROW / 128, HIDDEN / 128), dim3(256), 0, stream>>>(ab, wob, out, NROW, HIDDEN, HIDDEN);
}

// Round 12
// 506.179 us; speedup vs baseline: 1.2321x; 1.2321x over previous
//
#include <hip/hip_runtime.h>
#include <hip/hip_bf16.h>
#include <math.h>

#define HIDDEN 2048
#define NH 16
#define HD 128
#define SEQ 2048
#define BATCH 2
#define NROW (BATCH*SEQ)   // 4096

typedef unsigned short u16;
typedef unsigned int   u32;
typedef unsigned long long u64;
typedef __bf16 bf16x8 __attribute__((ext_vector_type(8)));
typedef float  f32x4  __attribute__((ext_vector_type(4)));

__device__ __forceinline__ u16 f2bf(float f){
  u32 u = __float_as_uint(f);
  u32 r = (u + 0x7fffu + ((u >> 16) & 1u)) >> 16;   // RNE
  return (u16)r;
}
__device__ __forceinline__ float bf2f(u16 h){ return __uint_as_float(((u32)h) << 16); }

typedef const void __attribute__((address_space(1)))* gas1_ptr;
typedef void __attribute__((address_space(3)))*       las3_ptr;
__device__ __forceinline__ void gload16(const void* g, void* l){
  // async global->LDS, 16B/lane; LDS dest = wave-uniform base + lane*16
  __builtin_amdgcn_global_load_lds((gas1_ptr)g, (las3_ptr)l, 16, 0, 0);
}

// ---------------- cast fp32 -> bf16 ----------------
__global__ void cast_kernel(const float* __restrict__ src, u16* __restrict__ dst, int n4){
  int i = blockIdx.x * blockDim.x + threadIdx.x;
  if (i >= n4) return;
  float4 v = reinterpret_cast<const float4*>(src)[i];
  ushort4 o;
  o.x = f2bf(v.x); o.y = f2bf(v.y); o.z = f2bf(v.z); o.w = f2bf(v.w);
  reinterpret_cast<ushort4*>(dst)[i] = o;
}

// ---------------- RoPE tables: cos/sin [SEQ][64] fp32 ----------------
__global__ void rope_table_kernel(float* __restrict__ cosT, float* __restrict__ sinT){
  int i = blockIdx.x * blockDim.x + threadIdx.x;
  if (i >= SEQ * 64) return;
  int s = i >> 6, d = i & 63;
  float invf = expf(-(float)d * 0.14391156830f);   // 10000^(-d/64)
  float ang = (float)s * invf;
  float sv, cv;
  sincosf(ang, &sv, &cv);
  cosT[i] = cv; sinT[i] = sv;
}

// ---------------- RoPE apply (in place on bf16 Q,K) ----------------
__global__ void rope_apply_kernel(u16* __restrict__ Q, u16* __restrict__ K,
                                  const float* __restrict__ cosT, const float* __restrict__ sinT){
  int i = blockIdx.x * blockDim.x + threadIdx.x;   // over NROW*NH*64
  if (i >= NROW * NH * 64) return;
  int d  = i & 63;
  int rh = i >> 6;                 // (b*SEQ+s)*NH + h
  int s  = (rh / NH) & (SEQ - 1);
  size_t base = (size_t)rh * HD;
  float c  = cosT[(s << 6) + d];
  float sn = sinT[(s << 6) + d];
  float q0 = bf2f(Q[base + d]), q1 = bf2f(Q[base + d + 64]);
  float k0 = bf2f(K[base + d]), k1 = bf2f(K[base + d + 64]);
  Q[base + d]      = f2bf(q0 * c - q1 * sn);
  Q[base + d + 64] = f2bf(q1 * c + q0 * sn);
  K[base + d]      = f2bf(k0 * c - k1 * sn);
  K[base + d + 64] = f2bf(k1 * c + k0 * sn);
}

// ---------------- GEMM C[M][N] = A[M][K] * B[N][K]^T (both bf16, K contiguous) ----------------
// m97 structure: 128x128 tile, BK=32, 4 waves (2x2), global_load_lds width 16, 2 barriers/K-step.
template<int BF16OUT>
__global__ __launch_bounds__(256) void gemm_bt_kernel(
    const u16* __restrict__ A, const u16* __restrict__ B, void* __restrict__ C,
    int M, int N, int K)
{
  __shared__ __align__(16) u16 As[128 * 32];
  __shared__ __align__(16) u16 Bs[128 * 32];
  const int tid  = threadIdx.x;
  const int wid  = tid >> 6;
  const int lane = tid & 63;
  const int lrow = lane & 15, lk = lane >> 4;
  const int wr = wid >> 1, wc = wid & 1;
  const int row0 = blockIdx.x * 128, col0 = blockIdx.y * 128;

  f32x4 acc[4][4];
  #pragma unroll
  for (int m = 0; m < 4; m++)
    #pragma unroll
    for (int n = 0; n < 4; n++) acc[m][n] = (f32x4){0.f, 0.f, 0.f, 0.f};

  const int arow = tid >> 2;            // 0..63 per staging round
  const int acol = (tid & 3) * 8;
  const u16* Ag = A + (size_t)(row0 + arow) * K + acol;
  const u16* Bg = B + (size_t)(col0 + arow) * K + acol;
  u16* AsW = As + wid * 512;            // wave-uniform LDS base
  u16* BsW = Bs + wid * 512;

  for (int k0 = 0; k0 < K; k0 += 32){
    gload16(Ag + k0,          AsW);
    gload16(Ag + 64 * K + k0, AsW + 2048);
    gload16(Bg + k0,          BsW);
    gload16(Bg + 64 * K + k0, BsW + 2048);
    __syncthreads();
    bf16x8 af[4], bfv[4];
    #pragma unroll
    for (int m = 0; m < 4; m++) af[m]  = *(const bf16x8*)&As[(wr * 64 + m * 16 + lrow) * 32 + lk * 8];
    #pragma unroll
    for (int n = 0; n < 4; n++) bfv[n] = *(const bf16x8*)&Bs[(wc * 64 + n * 16 + lrow) * 32 + lk * 8];
    #pragma unroll
    for (int m = 0; m < 4; m++)
      #pragma unroll
      for (int n = 0; n < 4; n++)
        acc[m][n] = __builtin_amdgcn_mfma_f32_16x16x32_bf16(af[m], bfv[n], acc[m][n], 0, 0, 0);
    __syncthreads();
  }

  #pragma unroll
  for (int m = 0; m < 4; m++){
    const int r = row0 + wr * 64 + m * 16 + lk * 4;
    #pragma unroll
    for (int n = 0; n < 4; n++){
      const int c = col0 + wc * 64 + n * 16 + lrow;
      #pragma unroll
      for (int j = 0; j < 4; j++){
        float v = acc[m][n][j];
        if constexpr (BF16OUT) ((u16*)C)[(size_t)(r + j) * N + c] = f2bf(v);
        else                   ((float*)C)[(size_t)(r + j) * N + c] = v;
      }
    }
  }
}

// ---------------- Flash attention fwd (v2.1: swapped QK^T, tr_read PV, KVBLK=64) ------
// grid (SEQ/64, NH, BATCH), 256 threads = 4 waves; wave owns 16 q-rows; KV tiles of 64.
__global__ __launch_bounds__(256) void attn_kernel(
    const u16* __restrict__ Q, const u16* __restrict__ K,
    const u16* __restrict__ V, u16* __restrict__ O)
{
  // Ks: [key][d] row-major, 16B-chunk swizzle: phys_chunk = chunk ^ (key&7)
  __shared__ __align__(128) u16 Ks[64 * 128];
  // Vs: subtiled [kb=key>>2][db=d>>4][key&3][d&15] for ds_read_b64_tr_b16.
  // 128B alignment REQUIRED: tr_read decomposes addr at 128B block boundary
  // (model consistent with m156 canonical-pattern + m162 uniform-addr probes).
  __shared__ __align__(128) u16 Vs[64 * 128];
  const int tid = threadIdx.x, wid = tid >> 6, lane = tid & 63;
  const int lrow = lane & 15, lk = lane >> 4;
  const int b = blockIdx.z, h = blockIdx.y;
  const int q0w = blockIdx.x * 64 + wid * 16;

  const float SCL = 0.08838834764831845f * 1.4426950408889634f;  // 1/sqrt(128) * log2(e)

  // Q as B-frag (n = q = lane&15, k = d), pre-scaled by SCL
  bf16x8 qf[4];
  {
    const u16* qrow = Q + ((size_t)((b * SEQ + q0w + lrow) * NH) + h) * HD;
    #pragma unroll
    for (int kc = 0; kc < 4; kc++){
      union { bf16x8 v; u16 s[8]; } u;
      u.v = *(const bf16x8*)(qrow + kc * 32 + lk * 8);
      #pragma unroll
      for (int j = 0; j < 8; j++) u.s[j] = f2bf(bf2f(u.s[j]) * SCL);
      qf[kc] = u.v;
    }
  }

  f32x4 accO[8];
  #pragma unroll
  for (int i = 0; i < 8; i++) accO[i] = (f32x4){0.f, 0.f, 0.f, 0.f};
  float mrun = -1e30f, lrun = 0.f;   // per lane: q = lane&15

  const u16* Kbase = K + (size_t)(b * SEQ) * (NH * HD) + h * HD;
  const u16* Vbase = V + (size_t)(b * SEQ) * (NH * HD) + h * HD;
  const u32 vsbase = (u32)(size_t)(las3_ptr)&Vs[0];
  // tr_read window addressing: lane (g=lk, w=lrow) supplies window byte
  // g*1024 + w*8 (+ dn*128 + s*4096 via offset imm); delivers
  // elem j = V[key = g*4 + s*16 + j][d = dn*16 + w].
  const u32 vaddr  = vsbase + (u32)(lk * 1024 + lrow * 8);

  // staging lane decomposition (per wave: 16 keys via 4 rounds)
  const int ksub = lane >> 4;          // K: key within round
  const int kchk = lane & 15;          // K: data chunk (d/8)
  const int vsub = (lane >> 1) & 3;    // V: key within round
  const int vd   = (lane >> 3) * 16 + (lane & 1) * 8;   // V: d offset

  for (int kv = 0; kv < SEQ; kv += 64){
    __syncthreads();
    // ---- stage K rows [wid*16 .. +15], swizzled source (rule #21) ----
    #pragma unroll
    for (int r = 0; r < 4; r++){
      int kl = wid * 16 + r * 4 + ksub;
      int cd = kchk ^ ((r * 4 + ksub) & 7);
      gload16(Kbase + (size_t)(kv + kl) * (NH * HD) + cd * 8,
              (char*)Ks + (size_t)(wid * 16 + r * 4) * 256);
    }
    // ---- stage V subtiled: kb = wid*4+r covers keys wid*16+r*4+{0..3}, all d ----
    #pragma unroll
    for (int r = 0; r < 4; r++){
      int kl = wid * 16 + r * 4 + vsub;
      gload16(Vbase + (size_t)(kv + kl) * (NH * HD) + vd,
              (char*)Vs + (size_t)(wid * 4 + r) * 1024);
    }
    __syncthreads();

    // ---- S^T = K Q^T : A=K (m=key), B=Q (n=q); 4 key-blocks x 4 d-chunks ----
    f32x4 accS[4];
    #pragma unroll
    for (int mb = 0; mb < 4; mb++) accS[mb] = (f32x4){0.f, 0.f, 0.f, 0.f};
    #pragma unroll
    for (int mb = 0; mb < 4; mb++){
      const int key = mb * 16 + lrow;
      #pragma unroll
      for (int kc = 0; kc < 4; kc++){
        int pc = (kc * 4 + lk) ^ (key & 7);
        bf16x8 kf = *(const bf16x8*)&Ks[key * 128 + pc * 8];
        accS[mb] = __builtin_amdgcn_mfma_f32_16x16x32_bf16(kf, qf[kc], accS[mb], 0, 0, 0);
      }
    }
    // lane now holds S[key = mb*16 + lk*4 + j][q = lane&15] (pre-scaled by SCL)

    // ---- online softmax, lane-local over 16 values + 2 shfl across lk groups ----
    float su[4][4];
    float tmax = -1e30f;
    #pragma unroll
    for (int mb = 0; mb < 4; mb++)
      #pragma unroll
      for (int j = 0; j < 4; j++){ su[mb][j] = accS[mb][j]; tmax = fmaxf(tmax, su[mb][j]); }
    tmax = fmaxf(tmax, __shfl_xor(tmax, 16));
    tmax = fmaxf(tmax, __shfl_xor(tmax, 32));
    float mnew = fmaxf(mrun, tmax);
    if (!__all(mnew == mrun)){           // exact defer-max: rescale only on new max
      float alpha = exp2f(mrun - mnew);
      mrun = mnew;
      lrun *= alpha;
      float aj[4];
      #pragma unroll
      for (int j = 0; j < 4; j++) aj[j] = __shfl(alpha, lk * 4 + j, 64);
      #pragma unroll
      for (int dn = 0; dn < 8; dn++)
        #pragma unroll
        for (int j = 0; j < 4; j++) accO[dn][j] *= aj[j];
    }
    float rsum = 0.f;
    float p[4][4];
    #pragma unroll
    for (int mb = 0; mb < 4; mb++)
      #pragma unroll
      for (int j = 0; j < 4; j++){ p[mb][j] = exp2f(su[mb][j] - mrun); rsum += p[mb][j]; }
    rsum += __shfl_xor(rsum, 16);
    rsum += __shfl_xor(rsum, 32);
    lrun += rsum;

    // ---- pack P as PV A-frag: hw-k = lk*8+e -> key = lk*4 + (e>=4)*16 + (e&3) ----
    union { u16 s[8]; bf16x8 v; } pk0, pk1;
    #pragma unroll
    for (int j = 0; j < 4; j++){
      pk0.s[j]     = f2bf(p[0][j]);
      pk0.s[4 + j] = f2bf(p[1][j]);
      pk1.s[j]     = f2bf(p[2][j]);
      pk1.s[4 + j] = f2bf(p[3][j]);
    }

    // ---- O += P V via hw-transpose reads of Vs (B-frag: n=d, k=key) ----
    #pragma unroll
    for (int dn = 0; dn < 8; dn++){
      u64 t0, t1, t2, t3;
      asm volatile("ds_read_b64_tr_b16 %0, %1 offset:%c2" : "=v"(t0) : "v"(vaddr), "i"(dn * 128));
      asm volatile("ds_read_b64_tr_b16 %0, %1 offset:%c2" : "=v"(t1) : "v"(vaddr), "i"(4096 + dn * 128));
      asm volatile("ds_read_b64_tr_b16 %0, %1 offset:%c2" : "=v"(t2) : "v"(vaddr), "i"(8192 + dn * 128));
      asm volatile("ds_read_b64_tr_b16 %0, %1 offset:%c2" : "=v"(t3) : "v"(vaddr), "i"(12288 + dn * 128));
      asm volatile("s_waitcnt lgkmcnt(0)");
      __builtin_amdgcn_sched_barrier(0);          // rule #18
      union { u64 q[2]; bf16x8 v; } vb0, vb1;
      vb0.q[0] = t0; vb0.q[1] = t1;
      vb1.q[0] = t2; vb1.q[1] = t3;
      accO[dn] = __builtin_amdgcn_mfma_f32_16x16x32_bf16(pk0.v, vb0.v, accO[dn], 0, 0, 0);
      accO[dn] = __builtin_amdgcn_mfma_f32_16x16x32_bf16(pk1.v, vb1.v, accO[dn], 0, 0, 0);
    }
  }

  // ---- epilogue: O rows q = lk*4+j, cols d = dn*16 + lane&15 ----
  float linv[4];
  #pragma unroll
  for (int j = 0; j < 4; j++) linv[j] = 1.0f / __shfl(lrun, lk * 4 + j, 64);
  #pragma unroll
  for (int dn = 0; dn < 8; dn++){
    #pragma unroll
    for (int j = 0; j < 4; j++){
      int qq = q0w + lk * 4 + j;
      O[((size_t)(b * SEQ + qq) * NH + h) * HD + dn * 16 + lrow] = f2bf(accO[dn][j] * linv[j]);
    }
  }
}

// ---------------- launch ----------------
extern "C" void kernel_launch(void* const* d_in, const int* in_sizes, int n_in,
                              void* d_out, int out_size, void* d_ws, size_t ws_size,
                              hipStream_t stream){
  const float* hs = (const float*)d_in[0];
  const float* wq = (const float*)d_in[1];
  const float* wk = (const float*)d_in[2];
  const float* wv = (const float*)d_in[3];
  const float* wo = (const float*)d_in[4];
  float* out = (float*)d_out;

  char* ws = (char*)d_ws;
  const size_t NEL_HS = (size_t)NROW * HIDDEN;    // 8,388,608
  const size_t NEL_W  = (size_t)HIDDEN * HIDDEN;  // 4,194,304
  u16* hsb = (u16*)ws; ws += NEL_HS * 2;
  u16* wqb = (u16*)ws; ws += NEL_W * 2;
  u16* wkb = (u16*)ws; ws += NEL_W * 2;
  u16* wvb = (u16*)ws; ws += NEL_W * 2;
  u16* wob = (u16*)ws; ws += NEL_W * 2;
  u16* qb  = (u16*)ws; ws += NEL_HS * 2;
  u16* kb  = (u16*)ws; ws += NEL_HS * 2;
  u16* vb  = (u16*)ws; ws += NEL_HS * 2;
  u16* ab  = (u16*)ws; ws += NEL_HS * 2;
  float* cosT = (float*)ws; ws += (size_t)SEQ * 64 * 4;
  float* sinT = (float*)ws; ws += (size_t)SEQ * 64 * 4;

  cast_kernel<<<dim3((unsigned)(NEL_HS / 4 / 256)), dim3(256), 0, stream>>>(hs, hsb, (int)(NEL_HS / 4));
  cast_kernel<<<dim3((unsigned)(NEL_W  / 4 / 256)), dim3(256), 0, stream>>>(wq, wqb, (int)(NEL_W / 4));
  cast_kernel<<<dim3((unsigned)(NEL_W  / 4 / 256)), dim3(256), 0, stream>>>(wk, wkb, (int)(NEL_W / 4));
  cast_kernel<<<dim3((unsigned)(NEL_W  / 4 / 256)), dim3(256), 0, stream>>>(wv, wvb, (int)(NEL_W / 4));
  cast_kernel<<<dim3((unsigned)(NEL_W  / 4 / 256)), dim3(256), 0, stream>>>(wo, wob, (int)(NEL_W / 4));
  rope_table_kernel<<<dim3(SEQ * 64 / 256), dim3(256), 0, stream>>>(cosT, sinT);
  gemm_bt_kernel<1><<<dim3(NROW / 128, HIDDEN / 128), dim3(256), 0, stream>>>(hsb, wqb, qb, NROW, HIDDEN, HIDDEN);
  gemm_bt_kernel<1><<<dim3(NROW / 128, HIDDEN / 128), dim3(256), 0, stream>>>(hsb, wkb, kb, NROW, HIDDEN, HIDDEN);
  gemm_bt_kernel<1><<<dim3(NROW / 128, HIDDEN / 128), dim3(256), 0, stream>>>(hsb, wvb, vb, NROW, HIDDEN, HIDDEN);
  rope_apply_kernel<<<dim3(NROW * NH * 64 / 256), dim3(256), 0, stream>>>(qb, kb, cosT, sinT);
  attn_kernel<<<dim3(SEQ / 64, NH, BATCH), dim3(256), 0, stream>>>(qb, kb, vb, ab);
  gemm_bt_kernel<0><<<dim3(NROW / 128, HIDDEN / 128), dim3(256), 0, stream>>>(ab, wob, out, NROW, HIDDEN, HIDDEN);
}